// Round 3
// baseline (424.456 us; speedup 1.0000x reference)
//
#include <hip/hip_runtime.h>
#include <hip/hip_bf16.h>
#include <cstdint>
#include <cstddef>

typedef __bf16 bf16_t;
typedef __bf16 bf16x8 __attribute__((ext_vector_type(8)));
typedef __bf16 bf16x4 __attribute__((ext_vector_type(4)));
typedef float  f32x4  __attribute__((ext_vector_type(4)));

#define M_DIM 16384   // B*S = 4*4096
#define N_DIM 3072    // 3*O
#define K_DIM 1024    // I
#define R_DIM 256
#define O_DIM 1024

#define BM 128
#define BN 128
#define BK 32

// ---------------------------------------------------------------------------
// Kernel 0: x (fp32) -> Xh (bf16). 16M elements, 8 per thread.
// ---------------------------------------------------------------------------
__global__ __launch_bounds__(256) void convert_x(
    const float* __restrict__ x, bf16_t* __restrict__ xh)
{
  const size_t base = ((size_t)blockIdx.x * 256 + threadIdx.x) * 8;
  const f32x4 v0 = *(const f32x4*)(x + base);
  const f32x4 v1 = *(const f32x4*)(x + base + 4);
  bf16x8 o;
  o[0] = (bf16_t)v0[0]; o[1] = (bf16_t)v0[1]; o[2] = (bf16_t)v0[2]; o[3] = (bf16_t)v0[3];
  o[4] = (bf16_t)v1[0]; o[5] = (bf16_t)v1[1]; o[6] = (bf16_t)v1[2]; o[7] = (bf16_t)v1[3];
  *(bf16x8*)(xh + base) = o;
}

// ---------------------------------------------------------------------------
// Kernel 1: Wf (bf16) = base_weight + [zeros(O); delta_K; delta_V]
// All inputs fp32. grid 384 x 256. Blocks [0,128): convert 8 Q-rows each.
// Blocks [128,384): 8 delta rows each (rows 1024..3071).
// delta[k][o][i] = vb[k][o] * sum_r vB[o][r]*vd[k][r]*vA[r][i]
// ---------------------------------------------------------------------------
__global__ __launch_bounds__(256) void prep_weight(
    const float* __restrict__ base_w,  // (3072, 1024)
    const float* __restrict__ vA,      // (256, 1024)
    const float* __restrict__ vB,      // (1024, 256)
    const float* __restrict__ vd,      // (2, 256)
    const float* __restrict__ vb,      // (2, 1024)
    bf16_t* __restrict__ Wf)           // (3072, 1024) bf16 out
{
  const int blk = blockIdx.x;
  const int t = threadIdx.x;

  if (blk < 128) {
    // convert Q rows fp32 -> bf16; thread t owns cols 4t..4t+3 of 8 rows
    const float* src = base_w + (size_t)blk * 8 * K_DIM;
    bf16_t*      dst = Wf + (size_t)blk * 8 * K_DIM;
#pragma unroll
    for (int rr = 0; rr < 8; ++rr) {
      const f32x4 v = *(const f32x4*)(src + rr * K_DIM + t * 4);
      bf16x4 ov;
      ov[0] = (bf16_t)v[0]; ov[1] = (bf16_t)v[1];
      ov[2] = (bf16_t)v[2]; ov[3] = (bf16_t)v[3];
      *(bf16x4*)(dst + rr * K_DIM + t * 4) = ov;
    }
    return;
  }

  const int rb = (blk - 128) * 8;   // delta-local row base 0..2040
  const int k  = rb >> 10;          // 0 = K-proj, 1 = V-proj (uniform per block)
  const int ob = rb & 1023;         // o base within this k

  __shared__ float coeffT[R_DIM][8];  // [r][row-in-block], 8 KB
  {
    const int r = t;  // 256 threads == R
    const float d = vd[k * R_DIM + r];
#pragma unroll
    for (int rr = 0; rr < 8; ++rr) {
      const int o = ob + rr;
      coeffT[r][rr] = vb[k * O_DIM + o] * vB[(size_t)o * R_DIM + r] * d;
    }
  }
  __syncthreads();

  // thread t owns columns 4t..4t+3 for all 8 rows of this block
  float acc[8][4];
#pragma unroll
  for (int rr = 0; rr < 8; ++rr)
#pragma unroll
    for (int c = 0; c < 4; ++c) acc[rr][c] = 0.0f;

  for (int r = 0; r < R_DIM; ++r) {
    const f32x4 av = *(const f32x4*)(vA + (size_t)r * K_DIM + t * 4);
    const f32x4 c0 = *(const f32x4*)&coeffT[r][0];
    const f32x4 c1 = *(const f32x4*)&coeffT[r][4];
#pragma unroll
    for (int rr = 0; rr < 8; ++rr) {
      const float cc = (rr < 4) ? c0[rr] : c1[rr - 4];
      acc[rr][0] += cc * av[0];
      acc[rr][1] += cc * av[1];
      acc[rr][2] += cc * av[2];
      acc[rr][3] += cc * av[3];
    }
  }

#pragma unroll
  for (int rr = 0; rr < 8; ++rr) {
    const size_t row = (size_t)(1024 + rb + rr);
    const f32x4 bw = *(const f32x4*)(base_w + row * K_DIM + t * 4);
    bf16x4 ov;
    ov[0] = (bf16_t)(bw[0] + acc[rr][0]);
    ov[1] = (bf16_t)(bw[1] + acc[rr][1]);
    ov[2] = (bf16_t)(bw[2] + acc[rr][2]);
    ov[3] = (bf16_t)(bw[3] + acc[rr][3]);
    *(bf16x4*)(Wf + row * K_DIM + t * 4) = ov;
  }
}

// ---------------------------------------------------------------------------
// Kernel 2: out(fp32) = X @ Wf^T + bias   (bf16 MFMA GEMM, B^T weights)
// 128x128 block tile, 4 waves (2x2), each wave 64x64 via 4x4 16x16x32 frags.
// PRECONV=true : A-tile staged from bf16 Xh (16B/lane).
// PRECONV=false: A-tile staged from fp32 X (2x16B/lane + cvt) — small-ws path.
// ---------------------------------------------------------------------------
template <bool PRECONV>
__global__ __launch_bounds__(256) void gemm_qkv(
    const bf16_t* __restrict__ Xh,    // (16384, 1024) bf16 (PRECONV)
    const float*  __restrict__ Xf,    // (16384, 1024) fp32 (!PRECONV)
    const bf16_t* __restrict__ W,     // (3072, 1024)  bf16 row-major (N,K)
    const float*  __restrict__ bias,  // (3072,) fp32
    float* __restrict__ out)          // (16384, 3072) fp32
{
  __shared__ bf16_t As[BM * BK];  // 8 KB, row-major, row stride BK (=64B)
  __shared__ bf16_t Bs[BN * BK];  // 8 KB

  const int bid = blockIdx.x;
  const int nt = bid % (N_DIM / BN);
  const int mt = bid / (N_DIM / BN);
  const int m0 = mt * BM;
  const int n0 = nt * BN;

  const int t = threadIdx.x;
  const int lane = t & 63;
  const int w = t >> 6;          // wave 0..3
  const int wm = w >> 1;         // wave row 0..1
  const int wn = w & 1;          // wave col 0..1

  // staging coords: thread t -> tile row sr (and sr+64), k-chunk sc (8 elems)
  const int sr = t >> 2;          // 0..63
  const int sc = (t & 3) * 8;     // 0,8,16,24

  const bf16_t* gB0 = W + (size_t)(n0 + sr) * K_DIM + sc;
  const bf16_t* gB1 = gB0 + (size_t)64 * K_DIM;

  bf16x8 ra0, ra1;
  uint4 rb0, rb1;

  const bf16_t* gA0h = Xh + (size_t)(m0 + sr) * K_DIM + sc;
  const bf16_t* gA1h = gA0h + (size_t)64 * K_DIM;
  const float*  gA0f = Xf + (size_t)(m0 + sr) * K_DIM + sc;
  const float*  gA1f = gA0f + (size_t)64 * K_DIM;

  // prefetch tile 0
  if (PRECONV) {
    ra0 = *(const bf16x8*)(gA0h);
    ra1 = *(const bf16x8*)(gA1h);
  } else {
    const f32x4 u0 = *(const f32x4*)(gA0f), u1 = *(const f32x4*)(gA0f + 4);
    const f32x4 u2 = *(const f32x4*)(gA1f), u3 = *(const f32x4*)(gA1f + 4);
#pragma unroll
    for (int c = 0; c < 4; ++c) { ra0[c] = (bf16_t)u0[c]; ra0[c + 4] = (bf16_t)u1[c]; }
#pragma unroll
    for (int c = 0; c < 4; ++c) { ra1[c] = (bf16_t)u2[c]; ra1[c + 4] = (bf16_t)u3[c]; }
  }
  rb0 = *(const uint4*)(gB0);
  rb1 = *(const uint4*)(gB1);

  const f32x4 zero4 = {0.0f, 0.0f, 0.0f, 0.0f};
  f32x4 acc[4][4];
#pragma unroll
  for (int i = 0; i < 4; ++i)
#pragma unroll
    for (int j = 0; j < 4; ++j) acc[i][j] = zero4;

  // fragment read coords (m89/m91-verified gemm_bt layout):
  // own-row = lane&15, k = (lane>>4)*8 + j  -> 16B contiguous ds_read_b128
  const int row_a = wm * 64 + (lane & 15);
  const int row_b = wn * 64 + (lane & 15);
  const int kb = (lane >> 4) * 8;

  for (int k0 = 0; k0 < K_DIM; k0 += BK) {
    // write current tile (prefetched regs) to LDS
    *(bf16x8*)(As + sr * BK + sc)        = ra0;
    *(bf16x8*)(As + (sr + 64) * BK + sc) = ra1;
    *(uint4*)(Bs + sr * BK + sc)         = rb0;
    *(uint4*)(Bs + (sr + 64) * BK + sc)  = rb1;
    __syncthreads();

    // prefetch next tile (latency hides behind this tile's ds_read + MFMA)
    if (k0 + BK < K_DIM) {
      if (PRECONV) {
        ra0 = *(const bf16x8*)(gA0h + k0 + BK);
        ra1 = *(const bf16x8*)(gA1h + k0 + BK);
      } else {
        const f32x4 u0 = *(const f32x4*)(gA0f + k0 + BK);
        const f32x4 u1 = *(const f32x4*)(gA0f + k0 + BK + 4);
        const f32x4 u2 = *(const f32x4*)(gA1f + k0 + BK);
        const f32x4 u3 = *(const f32x4*)(gA1f + k0 + BK + 4);
#pragma unroll
        for (int c = 0; c < 4; ++c) { ra0[c] = (bf16_t)u0[c]; ra0[c + 4] = (bf16_t)u1[c]; }
#pragma unroll
        for (int c = 0; c < 4; ++c) { ra1[c] = (bf16_t)u2[c]; ra1[c + 4] = (bf16_t)u3[c]; }
      }
      rb0 = *(const uint4*)(gB0 + k0 + BK);
      rb1 = *(const uint4*)(gB1 + k0 + BK);
    }

    bf16x8 a[4], b[4];
#pragma unroll
    for (int i = 0; i < 4; ++i)
      a[i] = *(const bf16x8*)(As + (row_a + i * 16) * BK + kb);
#pragma unroll
    for (int j = 0; j < 4; ++j)
      b[j] = *(const bf16x8*)(Bs + (row_b + j * 16) * BK + kb);

#pragma unroll
    for (int i = 0; i < 4; ++i)
#pragma unroll
      for (int j = 0; j < 4; ++j)
        acc[i][j] = __builtin_amdgcn_mfma_f32_16x16x32_bf16(a[i], b[j], acc[i][j], 0, 0, 0);

    __syncthreads();  // protect LDS before next iteration's ds_write
  }

  // epilogue: C/D layout col = lane&15 (n), row = (lane>>4)*4 + reg (m); fp32 out
  const int colg = lane & 15;
  const int rq = (lane >> 4) * 4;
#pragma unroll
  for (int j = 0; j < 4; ++j) {
    const int n = n0 + wn * 64 + j * 16 + colg;
    const float bv = bias[n];
#pragma unroll
    for (int i = 0; i < 4; ++i) {
      const size_t mb = (size_t)(m0 + wm * 64 + i * 16 + rq);
#pragma unroll
      for (int r = 0; r < 4; ++r)
        out[(mb + r) * N_DIM + n] = acc[i][j][r] + bv;
    }
  }
}

extern "C" void kernel_launch(void* const* d_in, const int* in_sizes, int n_in,
                              void* d_out, int out_size, void* d_ws, size_t ws_size,
                              hipStream_t stream) {
  const float* x      = (const float*)d_in[0];  // (4,4096,1024) fp32
  const float* base_w = (const float*)d_in[1];  // (3072,1024) fp32
  const float* base_b = (const float*)d_in[2];  // (3072,) fp32
  const float* vA     = (const float*)d_in[3];  // (256,1024) fp32
  const float* vB     = (const float*)d_in[4];  // (1024,256) fp32
  const float* vd     = (const float*)d_in[5];  // (2,256) fp32
  const float* vb     = (const float*)d_in[6];  // (2,1024) fp32
  float* out = (float*)d_out;                   // (16384,3072) fp32

  const size_t wf_bytes = (size_t)N_DIM * K_DIM * sizeof(bf16_t);  // 6.25 MB
  const size_t xh_off   = 8u * 1024 * 1024;                        // aligned 8 MB
  const size_t xh_bytes = (size_t)M_DIM * K_DIM * sizeof(bf16_t);  // 33.5 MB

  bf16_t* Wf = (bf16_t*)d_ws;
  prep_weight<<<384, 256, 0, stream>>>(base_w, vA, vB, vd, vb, Wf);

  const int gemm_grid = (M_DIM / BM) * (N_DIM / BN);  // 3072
  if (ws_size >= xh_off + xh_bytes) {
    bf16_t* Xh = (bf16_t*)((char*)d_ws + xh_off);
    convert_x<<<(M_DIM * K_DIM) / (256 * 8), 256, 0, stream>>>(x, Xh);
    gemm_qkv<true><<<gemm_grid, 256, 0, stream>>>(Xh, nullptr, Wf, base_b, out);
  } else {
    gemm_qkv<false><<<gemm_grid, 256, 0, stream>>>(nullptr, x, Wf, base_b, out);
  }
}